// Round 1
// baseline (582.164 us; speedup 1.0000x reference)
//
#include <hip/hip_runtime.h>
#include <stdint.h>
#include <stddef.h>

// MHA forward: B=4 T=2048 H=16 Dk=64 D=1024, fp32 in/out, fp16 MFMA internally.
// Pipeline: cvt weights -> 3 projection GEMMs -> flash attention -> output GEMM.

typedef __attribute__((ext_vector_type(4))) float f32x4;
typedef __attribute__((ext_vector_type(8))) _Float16 f16x8;
typedef __attribute__((ext_vector_type(4))) _Float16 f16x4;

#define DEV __device__ __forceinline__

constexpr int BATCH = 4, SEQ = 2048, NH = 16, DK = 64, DM = 1024;
constexpr int MROWS = BATCH * SEQ; // 8192

DEV void async16(const void* g, void* l) {
  // global -> LDS direct copy, 16B per lane, LDS dest = wave-uniform base + lane*16
  __builtin_amdgcn_global_load_lds(
      (const __attribute__((address_space(1))) unsigned int*)g,
      (__attribute__((address_space(3))) unsigned int*)l, 16, 0, 0);
}

// ---------------- weight fp32 -> fp16 (4 matrices of 1024x1024) ----------------
__global__ void cvt_w_kernel(const float* __restrict__ w0, const float* __restrict__ w1,
                             const float* __restrict__ w2, const float* __restrict__ w3,
                             _Float16* __restrict__ o0, _Float16* __restrict__ o1,
                             _Float16* __restrict__ o2, _Float16* __restrict__ o3) {
  size_t i = (size_t)blockIdx.x * blockDim.x + threadIdx.x; // one float4 per matrix
  const float* ws[4] = {w0, w1, w2, w3};
  _Float16* os[4] = {o0, o1, o2, o3};
#pragma unroll
  for (int m = 0; m < 4; m++) {
    f32x4 x = *(const f32x4*)(ws[m] + i * 4);
    f16x4 h;
#pragma unroll
    for (int j = 0; j < 4; j++) h[j] = (_Float16)x[j];
    *(f16x4*)(os[m] + i * 4) = h;
  }
}

// ---------------- GEMM: C[M,N] = A[M,K] * W[N,K]^T + bias ----------------
// A_F32: A is fp32 (convert during LDS staging) else fp16 (global_load_lds).
// MODE 0: store fp16 to [B,H,T,DK]   (Q, K)
// MODE 1: store fp16 to [B,H,DK,T]   (V transposed)
// MODE 2: store fp32 to [M, DM]      (final output)
template <bool A_F32, int MODE>
__global__ __launch_bounds__(256) void gemm_kernel(
    const void* __restrict__ Ap, const _Float16* __restrict__ Bw,
    const float* __restrict__ bias, void* __restrict__ Cp, float scale) {
  constexpr int K = DM;
  __shared__ __align__(16) _Float16 As[128 * 64];
  __shared__ __align__(16) _Float16 Bs[128 * 64];
  const int tid = threadIdx.x;
  const int wave = tid >> 6, lane = tid & 63;
  const int quad = lane >> 4, l16 = lane & 15;
  const int wm = wave >> 1, wn = wave & 1;
  const int m0 = blockIdx.y * 128, n0 = blockIdx.x * 128;

  const f32x4 zero4 = {0.f, 0.f, 0.f, 0.f};
  f32x4 acc[4][4];
#pragma unroll
  for (int mt = 0; mt < 4; mt++)
#pragma unroll
    for (int nt = 0; nt < 4; nt++) acc[mt][nt] = zero4;

  float bv[4];
#pragma unroll
  for (int nt = 0; nt < 4; nt++) bv[nt] = bias[n0 + wn * 64 + nt * 16 + l16];

  for (int kt = 0; kt < K / 64; kt++) {
    const int k0 = kt * 64;
    // stage B (weights, fp16) via async copy: tile [128 n][64 k]
#pragma unroll
    for (int it = 0; it < 4; it++) {
      int idx = it * 256 + tid;
      async16(Bw + (size_t)(n0 + (idx >> 3)) * K + k0 + (idx & 7) * 8,
              (char*)Bs + (size_t)(it * 256 + wave * 64) * 16);
    }
    if (A_F32) {
      const float* Af = (const float*)Ap;
#pragma unroll
      for (int it = 0; it < 4; it++) {
        int idx = it * 256 + tid;
        int row = idx >> 3, seg = idx & 7;
        const float* g = Af + (size_t)(m0 + row) * K + k0 + seg * 8;
        f32x4 x0 = *(const f32x4*)g;
        f32x4 x1 = *(const f32x4*)(g + 4);
        f16x8 h;
#pragma unroll
        for (int j = 0; j < 4; j++) { h[j] = (_Float16)x0[j]; h[4 + j] = (_Float16)x1[j]; }
        *(f16x8*)&As[row * 64 + seg * 8] = h;
      }
    } else {
      const _Float16* Ah = (const _Float16*)Ap;
#pragma unroll
      for (int it = 0; it < 4; it++) {
        int idx = it * 256 + tid;
        async16(Ah + (size_t)(m0 + (idx >> 3)) * K + k0 + (idx & 7) * 8,
                (char*)As + (size_t)(it * 256 + wave * 64) * 16);
      }
    }
    __syncthreads();
#pragma unroll
    for (int ks = 0; ks < 2; ks++) {
      f16x8 af[4], bfr[4];
#pragma unroll
      for (int mt = 0; mt < 4; mt++)
        af[mt] = *(const f16x8*)&As[(wm * 64 + mt * 16 + l16) * 64 + ks * 32 + quad * 8];
#pragma unroll
      for (int nt = 0; nt < 4; nt++)
        bfr[nt] = *(const f16x8*)&Bs[(wn * 64 + nt * 16 + l16) * 64 + ks * 32 + quad * 8];
#pragma unroll
      for (int mt = 0; mt < 4; mt++)
#pragma unroll
        for (int nt = 0; nt < 4; nt++)
          acc[mt][nt] = __builtin_amdgcn_mfma_f32_16x16x32_f16(af[mt], bfr[nt], acc[mt][nt], 0, 0, 0);
    }
    __syncthreads();
  }
  // epilogue: C/D layout row = quad*4+i, col = l16 (verified m89)
#pragma unroll
  for (int mt = 0; mt < 4; mt++)
#pragma unroll
    for (int nt = 0; nt < 4; nt++)
#pragma unroll
      for (int i = 0; i < 4; i++) {
        int m = m0 + wm * 64 + mt * 16 + quad * 4 + i;
        int n = n0 + wn * 64 + nt * 16 + l16;
        float val = (acc[mt][nt][i] + bv[nt]) * scale;
        if (MODE == 2) {
          ((float*)Cp)[(size_t)m * DM + n] = val;
        } else {
          int b = m >> 11, t = m & (SEQ - 1);
          int h = n >> 6, d = n & (DK - 1);
          _Float16 hv = (_Float16)val;
          if (MODE == 0)
            ((_Float16*)Cp)[(((size_t)(b * NH + h) * SEQ + t) << 6) + d] = hv;
          else
            ((_Float16*)Cp)[(((size_t)(b * NH + h) * DK + d) << 11) + t] = hv;
        }
      }
}

// ---------------- flash attention (causal), one 128-row Q tile per block ----------------
// Q,K: [B,H,T,64] fp16 ; V: [B,H,64,T] fp16 ; O: [B,T,H*64] fp16
__global__ __launch_bounds__(256) void attn_kernel(
    const _Float16* __restrict__ Q, const _Float16* __restrict__ Kt,
    const _Float16* __restrict__ V, _Float16* __restrict__ O) {
  __shared__ __align__(16) _Float16 Ks[128 * 64];   // [tk][d]
  __shared__ __align__(16) _Float16 Vs[64 * 128];   // [d][tk]
  __shared__ __align__(16) _Float16 Ps[4][32 * 72]; // per-wave P half-tile, stride 72 (pad)
  const int tid = threadIdx.x;
  const int wave = tid >> 6, lane = tid & 63, quad = lane >> 4, l16 = lane & 15;
  const int qt = blockIdx.x, bh = blockIdx.y;
  const int t0 = qt * 128;
  const size_t base = (size_t)bh * SEQ * DK;

  // Q fragments stay in registers: rows wave*32 + mt*16 + l16, k = ks*32 + quad*8
  f16x8 qf[2][2];
#pragma unroll
  for (int mt = 0; mt < 2; mt++)
#pragma unroll
    for (int ks = 0; ks < 2; ks++)
      qf[mt][ks] = *(const f16x8*)(Q + base + (size_t)(t0 + wave * 32 + mt * 16 + l16) * DK +
                                   ks * 32 + quad * 8);

  const f32x4 zero4 = {0.f, 0.f, 0.f, 0.f};
  f32x4 oacc[2][4];
#pragma unroll
  for (int mt = 0; mt < 2; mt++)
#pragma unroll
    for (int nt = 0; nt < 4; nt++) oacc[mt][nt] = zero4;
  float mrow[2][4], lrow[2][4];
#pragma unroll
  for (int mt = 0; mt < 2; mt++)
#pragma unroll
    for (int i = 0; i < 4; i++) { mrow[mt][i] = -1e30f; lrow[mt][i] = 0.f; }

  for (int j = 0; j <= qt; j++) {
    // stage K tile [128][64] and V tile [64][128]
#pragma unroll
    for (int it = 0; it < 4; it++) {
      int idx = it * 256 + tid;
      async16(Kt + base + (size_t)(j * 128 + (idx >> 3)) * DK + (idx & 7) * 8,
              (char*)Ks + (size_t)(it * 256 + wave * 64) * 16);
    }
#pragma unroll
    for (int it = 0; it < 4; it++) {
      int idx = it * 256 + tid;
      async16(V + base + ((size_t)(idx >> 4) << 11) + j * 128 + (idx & 15) * 8,
              (char*)Vs + (size_t)(it * 256 + wave * 64) * 16);
    }
    __syncthreads();

    // S = Q*K^T for this wave's 32 rows x 128 cols (Q pre-scaled by 0.125)
    f32x4 s[2][8];
#pragma unroll
    for (int nt = 0; nt < 8; nt++) {
      f16x8 b0 = *(const f16x8*)&Ks[(nt * 16 + l16) * 64 + quad * 8];
      f16x8 b1 = *(const f16x8*)&Ks[(nt * 16 + l16) * 64 + 32 + quad * 8];
#pragma unroll
      for (int mt = 0; mt < 2; mt++) {
        f32x4 z = zero4;
        z = __builtin_amdgcn_mfma_f32_16x16x32_f16(qf[mt][0], b0, z, 0, 0, 0);
        z = __builtin_amdgcn_mfma_f32_16x16x32_f16(qf[mt][1], b1, z, 0, 0, 0);
        s[mt][nt] = z;
      }
    }
    if (j == qt) { // diagonal tile: causal mask col > row
#pragma unroll
      for (int mt = 0; mt < 2; mt++)
#pragma unroll
        for (int i = 0; i < 4; i++) {
          int row = wave * 32 + mt * 16 + quad * 4 + i;
#pragma unroll
          for (int nt = 0; nt < 8; nt++)
            if (nt * 16 + l16 > row) s[mt][nt][i] = -1e30f;
        }
    }
    // online softmax, rows owned by 16-lane groups (same quad)
#pragma unroll
    for (int mt = 0; mt < 2; mt++)
#pragma unroll
      for (int i = 0; i < 4; i++) {
        float mx = mrow[mt][i];
#pragma unroll
        for (int nt = 0; nt < 8; nt++) mx = fmaxf(mx, s[mt][nt][i]);
#pragma unroll
        for (int off = 8; off >= 1; off >>= 1) mx = fmaxf(mx, __shfl_xor(mx, off));
        float alpha = __expf(mrow[mt][i] - mx);
        mrow[mt][i] = mx;
        float rs = 0.f;
#pragma unroll
        for (int nt = 0; nt < 8; nt++) {
          float p = __expf(s[mt][nt][i] - mx);
          s[mt][nt][i] = p;
          rs += p;
        }
#pragma unroll
        for (int off = 8; off >= 1; off >>= 1) rs += __shfl_xor(rs, off);
        lrow[mt][i] = lrow[mt][i] * alpha + rs;
#pragma unroll
        for (int nt = 0; nt < 4; nt++) oacc[mt][nt][i] *= alpha;
      }
    // P*V: round-trip P through per-wave LDS (C-layout -> A-layout), 2 k-halves
#pragma unroll
    for (int h = 0; h < 2; h++) {
#pragma unroll
      for (int mt = 0; mt < 2; mt++)
#pragma unroll
        for (int nt = 0; nt < 4; nt++)
#pragma unroll
          for (int i = 0; i < 4; i++)
            Ps[wave][(mt * 16 + quad * 4 + i) * 72 + nt * 16 + l16] =
                (_Float16)s[mt][h * 4 + nt][i];
#pragma unroll
      for (int ks = 0; ks < 2; ks++) {
        f16x8 pa[2];
#pragma unroll
        for (int mt = 0; mt < 2; mt++)
          pa[mt] = *(const f16x8*)&Ps[wave][(mt * 16 + l16) * 72 + ks * 32 + quad * 8];
        int gk = h * 64 + ks * 32;
#pragma unroll
        for (int nt = 0; nt < 4; nt++) {
          f16x8 vb = *(const f16x8*)&Vs[(nt * 16 + l16) * 128 + gk + quad * 8];
#pragma unroll
          for (int mt = 0; mt < 2; mt++)
            oacc[mt][nt] = __builtin_amdgcn_mfma_f32_16x16x32_f16(pa[mt], vb, oacc[mt][nt], 0, 0, 0);
        }
      }
    }
    __syncthreads();
  }
  // epilogue: normalize and store to [B,T,H*64]
  const int b = bh >> 4, h = bh & 15;
#pragma unroll
  for (int mt = 0; mt < 2; mt++)
#pragma unroll
    for (int i = 0; i < 4; i++) {
      float inv = 1.0f / lrow[mt][i];
      int t = t0 + wave * 32 + mt * 16 + quad * 4 + i;
#pragma unroll
      for (int nt = 0; nt < 4; nt++) {
        int d = nt * 16 + l16;
        O[((size_t)(b * SEQ + t) << 10) + h * 64 + d] = (_Float16)(oacc[mt][nt][i] * inv);
      }
    }
}

extern "C" void kernel_launch(void* const* d_in, const int* in_sizes, int n_in,
                              void* d_out, int out_size, void* d_ws, size_t ws_size,
                              hipStream_t stream) {
  const float* query = (const float*)d_in[0];
  const float* key_  = (const float*)d_in[1];
  const float* value = (const float*)d_in[2];
  // d_in[3] = causal mask, implemented analytically
  const float* W_q = (const float*)d_in[4];
  const float* b_q = (const float*)d_in[5];
  const float* W_k = (const float*)d_in[6];
  const float* b_k = (const float*)d_in[7];
  const float* W_v = (const float*)d_in[8];
  const float* b_v = (const float*)d_in[9];
  const float* W_o = (const float*)d_in[10];
  const float* b_o = (const float*)d_in[11];

  constexpr size_t WEL = (size_t)DM * DM;    // 1M
  constexpr size_t MEL = (size_t)MROWS * DM; // 8M
  _Float16* ws = (_Float16*)d_ws;
  _Float16* wq = ws;
  _Float16* wk = wq + WEL;
  _Float16* wv = wk + WEL;
  _Float16* wo = wv + WEL;
  _Float16* qb = wo + WEL;
  _Float16* kb = qb + MEL;
  _Float16* vb = kb + MEL;
  _Float16* ab = vb + MEL; // total 75.5 MB of workspace

  cvt_w_kernel<<<dim3((unsigned)(WEL / 4 / 256)), 256, 0, stream>>>(
      W_q, W_k, W_v, W_o, wq, wk, wv, wo);
  dim3 gg(DM / 128, MROWS / 128);
  gemm_kernel<true, 0><<<gg, 256, 0, stream>>>(query, wq, b_q, qb, 0.125f); // scale folded into Q
  gemm_kernel<true, 0><<<gg, 256, 0, stream>>>(key_, wk, b_k, kb, 1.0f);
  gemm_kernel<true, 1><<<gg, 256, 0, stream>>>(value, wv, b_v, vb, 1.0f);
  attn_kernel<<<dim3(SEQ / 128, BATCH * NH), 256, 0, stream>>>(qb, kb, vb, ab);
  gemm_kernel<false, 2><<<gg, 256, 0, stream>>>(ab, wo, b_o, d_out, 1.0f);
}

// Round 3
// 475.017 us; speedup vs baseline: 1.2256x; 1.2256x over previous
//
#include <hip/hip_runtime.h>
#include <stdint.h>
#include <stddef.h>

// MHA forward: B=4 T=2048 H=16 Dk=64 D=1024, fp32 in/out, fp16 MFMA internally.
// Pipeline: cvt weights -> fused QKV GEMM -> balanced flash attention -> output GEMM.

typedef __attribute__((ext_vector_type(4))) float f32x4;
typedef __attribute__((ext_vector_type(8))) _Float16 f16x8;
typedef __attribute__((ext_vector_type(4))) _Float16 f16x4;

#define DEV __device__ __forceinline__

constexpr int BATCH = 4, SEQ = 2048, NH = 16, DK = 64, DM = 1024;
constexpr int MROWS = BATCH * SEQ; // 8192
// scores computed in log2 domain: fold 1/sqrt(64) * log2(e) into Q projection
constexpr float QSCALE = 0.125f * 1.4426950408889634f;

DEV void async16(const void* g, void* l) {
  __builtin_amdgcn_global_load_lds(
      (const __attribute__((address_space(1))) unsigned int*)g,
      (__attribute__((address_space(3))) unsigned int*)l, 16, 0, 0);
}

// ---------------- weight fp32 -> fp16 (4 matrices of 1024x1024) ----------------
__global__ void cvt_w_kernel(const float* __restrict__ w0, const float* __restrict__ w1,
                             const float* __restrict__ w2, const float* __restrict__ w3,
                             _Float16* __restrict__ o0, _Float16* __restrict__ o1,
                             _Float16* __restrict__ o2, _Float16* __restrict__ o3) {
  size_t i = (size_t)blockIdx.x * blockDim.x + threadIdx.x;
  const float* ws[4] = {w0, w1, w2, w3};
  _Float16* os[4] = {o0, o1, o2, o3};
#pragma unroll
  for (int m = 0; m < 4; m++) {
    f32x4 x = *(const f32x4*)(ws[m] + i * 4);
    f16x4 h;
#pragma unroll
    for (int j = 0; j < 4; j++) h[j] = (_Float16)x[j];
    *(f16x4*)(os[m] + i * 4) = h;
  }
}

struct QKVPtrs {
  const float* a[3];
  const _Float16* w[3];
  const float* bias[3];
  _Float16* out[3];
};

// ---------------- fused QKV GEMM: C = A[M,K] * W[N,K]^T + bias ----------------
// z=0: Q -> [B,H,T,64] (scaled by QSCALE); z=1: K -> [B,H,T,64]; z=2: V -> [B,H,64,T]
__global__ __launch_bounds__(256) void gemm_qkv_kernel(QKVPtrs P) {
  constexpr int K = DM;
  __shared__ __align__(16) _Float16 smem[128 * 144]; // staging (16K halves) / C-tile (18432 halves)
  _Float16* As = smem;
  _Float16* Bs = smem + 8192;
  const int z = blockIdx.z;
  const float* Af = P.a[z];
  const _Float16* Bw = P.w[z];
  const int tid = threadIdx.x;
  const int wave = tid >> 6, lane = tid & 63;
  const int quad = lane >> 4, l16 = lane & 15;
  const int wm = wave >> 1, wn = wave & 1;
  const int m0 = blockIdx.y * 128, n0 = blockIdx.x * 128;
  const float scale = (z == 0) ? QSCALE : 1.0f;

  const f32x4 zero4 = {0.f, 0.f, 0.f, 0.f};
  f32x4 acc[4][4];
#pragma unroll
  for (int mt = 0; mt < 4; mt++)
#pragma unroll
    for (int nt = 0; nt < 4; nt++) acc[mt][nt] = zero4;

  float bv[4];
#pragma unroll
  for (int nt = 0; nt < 4; nt++) bv[nt] = P.bias[z][n0 + wn * 64 + nt * 16 + l16];

  for (int kt = 0; kt < K / 64; kt++) {
    const int k0 = kt * 64;
#pragma unroll
    for (int it = 0; it < 4; it++) {
      int idx = it * 256 + tid;
      async16(Bw + (size_t)(n0 + (idx >> 3)) * K + k0 + (idx & 7) * 8,
              (char*)Bs + (size_t)(it * 256 + wave * 64) * 16);
    }
#pragma unroll
    for (int it = 0; it < 4; it++) {
      int idx = it * 256 + tid;
      int row = idx >> 3, seg = idx & 7;
      const float* g = Af + (size_t)(m0 + row) * K + k0 + seg * 8;
      f32x4 x0 = *(const f32x4*)g;
      f32x4 x1 = *(const f32x4*)(g + 4);
      f16x8 h;
#pragma unroll
      for (int j = 0; j < 4; j++) { h[j] = (_Float16)x0[j]; h[4 + j] = (_Float16)x1[j]; }
      *(f16x8*)&As[row * 64 + seg * 8] = h;
    }
    __syncthreads();
#pragma unroll
    for (int ks = 0; ks < 2; ks++) {
      f16x8 af[4], bfr[4];
#pragma unroll
      for (int mt = 0; mt < 4; mt++)
        af[mt] = *(const f16x8*)&As[(wm * 64 + mt * 16 + l16) * 64 + ks * 32 + quad * 8];
#pragma unroll
      for (int nt = 0; nt < 4; nt++)
        bfr[nt] = *(const f16x8*)&Bs[(wn * 64 + nt * 16 + l16) * 64 + ks * 32 + quad * 8];
#pragma unroll
      for (int mt = 0; mt < 4; mt++)
#pragma unroll
        for (int nt = 0; nt < 4; nt++)
          acc[mt][nt] = __builtin_amdgcn_mfma_f32_16x16x32_f16(af[mt], bfr[nt], acc[mt][nt], 0, 0, 0);
    }
    __syncthreads();
  }

  // epilogue: stage fp16 C-tile in LDS (stride 144 halves, 16B-aligned rows), coalesced store
  _Float16* Ct = smem;
  const int b = m0 >> 11, tbase = m0 & (SEQ - 1);
  if (z < 2) { // Ct[m][n]
#pragma unroll
    for (int mt = 0; mt < 4; mt++)
#pragma unroll
      for (int nt = 0; nt < 4; nt++)
#pragma unroll
        for (int i = 0; i < 4; i++)
          Ct[(wm * 64 + mt * 16 + quad * 4 + i) * 144 + wn * 64 + nt * 16 + l16] =
              (_Float16)((acc[mt][nt][i] + bv[nt]) * scale);
  } else { // Ct[n][m] (transposed for V)
#pragma unroll
    for (int mt = 0; mt < 4; mt++)
#pragma unroll
      for (int nt = 0; nt < 4; nt++)
#pragma unroll
        for (int i = 0; i < 4; i++)
          Ct[(wn * 64 + nt * 16 + l16) * 144 + wm * 64 + mt * 16 + quad * 4 + i] =
              (_Float16)(acc[mt][nt][i] + bv[nt]);
  }
  __syncthreads();
  _Float16* out = P.out[z];
  if (z < 2) {
    // per head-half: 128 t-rows x 64 d = contiguous region in [B,H,T,64]
    const int row = tid >> 1, coff = (tid & 1) * 32;
#pragma unroll
    for (int hh = 0; hh < 2; hh++) {
      int h = (n0 >> 6) + hh;
      size_t gb = ((size_t)(b * NH + h) * SEQ + tbase) * 64 + (size_t)tid * 32;
#pragma unroll
      for (int k2 = 0; k2 < 4; k2++)
        *(f16x8*)&out[gb + k2 * 8] =
            *(const f16x8*)&Ct[row * 144 + hh * 64 + coff + k2 * 8];
    }
  } else {
    // V: each n-row (d) is a 128-half t-slice of [B,H,64,T]; 8 iters cover 128x128
#pragma unroll
    for (int k2 = 0; k2 < 8; k2++) {
      int c = k2 * 256 + tid;        // 0..2047
      int n = c >> 4, s2 = c & 15;   // n: 0..127, s2: 0..15 (16 x 8 halves = 128 t)
      int h = (n0 + n) >> 6, d = (n0 + n) & (DK - 1);
      size_t gb = ((size_t)(b * NH + h) * DK + d) * SEQ + tbase + s2 * 8;
      *(f16x8*)&out[gb] = *(const f16x8*)&Ct[n * 144 + s2 * 8];
    }
  }
}

// ---------------- output GEMM: fp16 A, fp32 out [M, DM] ----------------
__global__ __launch_bounds__(256) void gemm_out_kernel(
    const _Float16* __restrict__ Ah, const _Float16* __restrict__ Bw,
    const float* __restrict__ bias, float* __restrict__ Cp) {
  constexpr int K = DM;
  __shared__ __align__(16) _Float16 As[128 * 64];
  __shared__ __align__(16) _Float16 Bs[128 * 64];
  const int tid = threadIdx.x;
  const int wave = tid >> 6, lane = tid & 63;
  const int quad = lane >> 4, l16 = lane & 15;
  const int wm = wave >> 1, wn = wave & 1;
  const int m0 = blockIdx.y * 128, n0 = blockIdx.x * 128;

  const f32x4 zero4 = {0.f, 0.f, 0.f, 0.f};
  f32x4 acc[4][4];
#pragma unroll
  for (int mt = 0; mt < 4; mt++)
#pragma unroll
    for (int nt = 0; nt < 4; nt++) acc[mt][nt] = zero4;

  float bv[4];
#pragma unroll
  for (int nt = 0; nt < 4; nt++) bv[nt] = bias[n0 + wn * 64 + nt * 16 + l16];

  for (int kt = 0; kt < K / 64; kt++) {
    const int k0 = kt * 64;
#pragma unroll
    for (int it = 0; it < 4; it++) {
      int idx = it * 256 + tid;
      async16(Bw + (size_t)(n0 + (idx >> 3)) * K + k0 + (idx & 7) * 8,
              (char*)Bs + (size_t)(it * 256 + wave * 64) * 16);
    }
#pragma unroll
    for (int it = 0; it < 4; it++) {
      int idx = it * 256 + tid;
      async16(Ah + (size_t)(m0 + (idx >> 3)) * K + k0 + (idx & 7) * 8,
              (char*)As + (size_t)(it * 256 + wave * 64) * 16);
    }
    __syncthreads();
#pragma unroll
    for (int ks = 0; ks < 2; ks++) {
      f16x8 af[4], bfr[4];
#pragma unroll
      for (int mt = 0; mt < 4; mt++)
        af[mt] = *(const f16x8*)&As[(wm * 64 + mt * 16 + l16) * 64 + ks * 32 + quad * 8];
#pragma unroll
      for (int nt = 0; nt < 4; nt++)
        bfr[nt] = *(const f16x8*)&Bs[(wn * 64 + nt * 16 + l16) * 64 + ks * 32 + quad * 8];
#pragma unroll
      for (int mt = 0; mt < 4; mt++)
#pragma unroll
        for (int nt = 0; nt < 4; nt++)
          acc[mt][nt] = __builtin_amdgcn_mfma_f32_16x16x32_f16(af[mt], bfr[nt], acc[mt][nt], 0, 0, 0);
    }
    __syncthreads();
  }
#pragma unroll
  for (int mt = 0; mt < 4; mt++)
#pragma unroll
    for (int nt = 0; nt < 4; nt++)
#pragma unroll
      for (int i = 0; i < 4; i++) {
        int m = m0 + wm * 64 + mt * 16 + quad * 4 + i;
        int n = n0 + wn * 64 + nt * 16 + l16;
        Cp[(size_t)m * DM + n] = acc[mt][nt][i] + bv[nt];
      }
}

// ---------------- balanced flash attention (causal) ----------------
// Each block handles Q-tiles {p, 15-p}: (p+1)+(16-p) = 17 k-tile iterations, uniform.
// Q,K: [B,H,T,64] fp16 (Q pre-scaled by QSCALE); V: [B,H,64,T] fp16; O: [B,T,H*64] fp16
__global__ __launch_bounds__(256) void attn_kernel(
    const _Float16* __restrict__ Q, const _Float16* __restrict__ Kt,
    const _Float16* __restrict__ V, _Float16* __restrict__ O) {
  __shared__ __align__(16) _Float16 Ks[128 * 64];   // [tk][d]
  __shared__ __align__(16) _Float16 Vs[64 * 128];   // [d][tk]
  __shared__ __align__(16) _Float16 Ps[4][32 * 80]; // per-wave P half-tile, stride 80 (16B-aligned)
  const int tid = threadIdx.x;
  const int wave = tid >> 6, lane = tid & 63, quad = lane >> 4, l16 = lane & 15;
  const int bh = blockIdx.y;
  const size_t base = (size_t)bh * SEQ * DK;
  const int b = bh >> 4, h = bh & 15;
  const f32x4 zero4 = {0.f, 0.f, 0.f, 0.f};

  for (int p = 0; p < 2; p++) {
    const int qt = (p == 0) ? (int)blockIdx.x : 15 - (int)blockIdx.x;
    const int t0 = qt * 128;

    f16x8 qf[2][2];
#pragma unroll
    for (int mt = 0; mt < 2; mt++)
#pragma unroll
      for (int ks = 0; ks < 2; ks++)
        qf[mt][ks] = *(const f16x8*)(Q + base + (size_t)(t0 + wave * 32 + mt * 16 + l16) * DK +
                                     ks * 32 + quad * 8);

    f32x4 oacc[2][4];
#pragma unroll
    for (int mt = 0; mt < 2; mt++)
#pragma unroll
      for (int nt = 0; nt < 4; nt++) oacc[mt][nt] = zero4;
    float mrow[2][4], lrow[2][4];
#pragma unroll
    for (int mt = 0; mt < 2; mt++)
#pragma unroll
      for (int i = 0; i < 4; i++) { mrow[mt][i] = -1e30f; lrow[mt][i] = 0.f; }

    for (int j = 0; j <= qt; j++) {
#pragma unroll
      for (int it = 0; it < 4; it++) {
        int idx = it * 256 + tid;
        async16(Kt + base + (size_t)(j * 128 + (idx >> 3)) * DK + (idx & 7) * 8,
                (char*)Ks + (size_t)(it * 256 + wave * 64) * 16);
      }
#pragma unroll
      for (int it = 0; it < 4; it++) {
        int idx = it * 256 + tid;
        async16(V + base + ((size_t)(idx >> 4) << 11) + j * 128 + (idx & 15) * 8,
                (char*)Vs + (size_t)(it * 256 + wave * 64) * 16);
      }
      __syncthreads();

      // S = Q*K^T (log2 domain), this wave's 32 rows x 128 cols
      f32x4 s[2][8];
#pragma unroll
      for (int nt = 0; nt < 8; nt++) {
        f16x8 b0 = *(const f16x8*)&Ks[(nt * 16 + l16) * 64 + quad * 8];
        f16x8 b1 = *(const f16x8*)&Ks[(nt * 16 + l16) * 64 + 32 + quad * 8];
#pragma unroll
        for (int mt = 0; mt < 2; mt++) {
          f32x4 zz = zero4;
          zz = __builtin_amdgcn_mfma_f32_16x16x32_f16(qf[mt][0], b0, zz, 0, 0, 0);
          zz = __builtin_amdgcn_mfma_f32_16x16x32_f16(qf[mt][1], b1, zz, 0, 0, 0);
          s[mt][nt] = zz;
        }
      }
      if (j == qt) { // diagonal: mask col > row
#pragma unroll
        for (int mt = 0; mt < 2; mt++)
#pragma unroll
          for (int i = 0; i < 4; i++) {
            int row = wave * 32 + mt * 16 + quad * 4 + i;
#pragma unroll
            for (int nt = 0; nt < 8; nt++)
              if (nt * 16 + l16 > row) s[mt][nt][i] = -1e30f;
          }
      }
      // online softmax (exp2), rows owned by 16-lane groups
#pragma unroll
      for (int mt = 0; mt < 2; mt++)
#pragma unroll
        for (int i = 0; i < 4; i++) {
          float mx = mrow[mt][i];
#pragma unroll
          for (int nt = 0; nt < 8; nt++) mx = fmaxf(mx, s[mt][nt][i]);
#pragma unroll
          for (int off = 8; off >= 1; off >>= 1) mx = fmaxf(mx, __shfl_xor(mx, off));
          float alpha = __builtin_exp2f(mrow[mt][i] - mx);
          mrow[mt][i] = mx;
          float rs = 0.f;
#pragma unroll
          for (int nt = 0; nt < 8; nt++) {
            float pv = __builtin_exp2f(s[mt][nt][i] - mx);
            s[mt][nt][i] = pv;
            rs += pv;
          }
#pragma unroll
          for (int off = 8; off >= 1; off >>= 1) rs += __shfl_xor(rs, off);
          lrow[mt][i] = lrow[mt][i] * alpha + rs;
#pragma unroll
          for (int nt = 0; nt < 4; nt++) oacc[mt][nt][i] *= alpha;
        }
      // P*V via per-wave LDS round-trip (C-layout -> A-layout), 2 k-halves
#pragma unroll
      for (int kh = 0; kh < 2; kh++) {
#pragma unroll
        for (int mt = 0; mt < 2; mt++)
#pragma unroll
          for (int nt = 0; nt < 4; nt++)
#pragma unroll
            for (int i = 0; i < 4; i++)
              Ps[wave][(mt * 16 + quad * 4 + i) * 80 + nt * 16 + l16] =
                  (_Float16)s[mt][kh * 4 + nt][i];
#pragma unroll
        for (int ks = 0; ks < 2; ks++) {
          f16x8 pa[2];
#pragma unroll
          for (int mt = 0; mt < 2; mt++)
            pa[mt] = *(const f16x8*)&Ps[wave][(mt * 16 + l16) * 80 + ks * 32 + quad * 8];
          int gk = kh * 64 + ks * 32;
#pragma unroll
          for (int nt = 0; nt < 4; nt++) {
            f16x8 vb = *(const f16x8*)&Vs[(nt * 16 + l16) * 128 + gk + quad * 8];
#pragma unroll
            for (int mt = 0; mt < 2; mt++)
              oacc[mt][nt] = __builtin_amdgcn_mfma_f32_16x16x32_f16(pa[mt], vb, oacc[mt][nt], 0, 0, 0);
          }
        }
      }
      __syncthreads();
    }
    // epilogue: normalize and store this pass's rows
#pragma unroll
    for (int mt = 0; mt < 2; mt++)
#pragma unroll
      for (int i = 0; i < 4; i++) {
        float inv = 1.0f / lrow[mt][i];
        int t = t0 + wave * 32 + mt * 16 + quad * 4 + i;
#pragma unroll
        for (int nt = 0; nt < 4; nt++) {
          int d = nt * 16 + l16;
          O[((size_t)(b * SEQ + t) << 10) + h * 64 + d] = (_Float16)(oacc[mt][nt][i] * inv);
        }
      }
  }
}

extern "C" void kernel_launch(void* const* d_in, const int* in_sizes, int n_in,
                              void* d_out, int out_size, void* d_ws, size_t ws_size,
                              hipStream_t stream) {
  const float* query = (const float*)d_in[0];
  const float* key_  = (const float*)d_in[1];
  const float* value = (const float*)d_in[2];
  // d_in[3] = causal mask, implemented analytically
  const float* W_q = (const float*)d_in[4];
  const float* b_q = (const float*)d_in[5];
  const float* W_k = (const float*)d_in[6];
  const float* b_k = (const float*)d_in[7];
  const float* W_v = (const float*)d_in[8];
  const float* b_v = (const float*)d_in[9];
  const float* W_o = (const float*)d_in[10];
  const float* b_o = (const float*)d_in[11];

  constexpr size_t WEL = (size_t)DM * DM;    // 1M
  constexpr size_t MEL = (size_t)MROWS * DM; // 8M
  _Float16* ws = (_Float16*)d_ws;
  _Float16* wq = ws;
  _Float16* wk = wq + WEL;
  _Float16* wv = wk + WEL;
  _Float16* wo = wv + WEL;
  _Float16* qb = wo + WEL;
  _Float16* kb = qb + MEL;
  _Float16* vb = kb + MEL;
  _Float16* ab = vb + MEL; // total 75.5 MB

  cvt_w_kernel<<<dim3((unsigned)(WEL / 4 / 256)), 256, 0, stream>>>(
      W_q, W_k, W_v, W_o, wq, wk, wv, wo);

  QKVPtrs P;
  P.a[0] = query; P.a[1] = key_; P.a[2] = value;
  P.w[0] = wq;    P.w[1] = wk;   P.w[2] = wv;
  P.bias[0] = b_q; P.bias[1] = b_k; P.bias[2] = b_v;
  P.out[0] = qb;  P.out[1] = kb;  P.out[2] = vb;
  gemm_qkv_kernel<<<dim3(DM / 128, MROWS / 128, 3), 256, 0, stream>>>(P);

  attn_kernel<<<dim3(8, BATCH * NH), 256, 0, stream>>>(qb, kb, vb, ab);

  gemm_out_kernel<<<dim3(DM / 128, MROWS / 128), 256, 0, stream>>>(ab, wo, b_o, (float*)d_out);
}

// Round 4
// 364.432 us; speedup vs baseline: 1.5975x; 1.3034x over previous
//
#include <hip/hip_runtime.h>
#include <stdint.h>
#include <stddef.h>

// MHA forward: B=4 T=2048 H=16 Dk=64 D=1024, fp32 in/out, fp16 MFMA internally.
// cvt weights(+acts) -> fused QKV GEMM -> transposed-score flash attention -> output GEMM.

typedef __attribute__((ext_vector_type(4))) float f32x4;
typedef __attribute__((ext_vector_type(8))) _Float16 f16x8;
typedef __attribute__((ext_vector_type(4))) _Float16 f16x4;

#define DEV __device__ __forceinline__

constexpr int BATCH = 4, SEQ = 2048, NH = 16, DK = 64, DM = 1024;
constexpr int MROWS = BATCH * SEQ; // 8192
// log2-domain softmax: fold 1/sqrt(64) * log2(e) into Q projection
constexpr float QSCALE = 0.125f * 1.4426950408889634f;

DEV void async16(const void* g, void* l) {
  __builtin_amdgcn_global_load_lds(
      (const __attribute__((address_space(1))) unsigned int*)g,
      (__attribute__((address_space(3))) unsigned int*)l, 16, 0, 0);
}

// ---------------- fp32 -> fp16 converters ----------------
__global__ void cvt_w_kernel(const float* __restrict__ w0, const float* __restrict__ w1,
                             const float* __restrict__ w2, const float* __restrict__ w3,
                             _Float16* __restrict__ o0, _Float16* __restrict__ o1,
                             _Float16* __restrict__ o2, _Float16* __restrict__ o3) {
  size_t i = (size_t)blockIdx.x * blockDim.x + threadIdx.x;
  const float* ws[4] = {w0, w1, w2, w3};
  _Float16* os[4] = {o0, o1, o2, o3};
#pragma unroll
  for (int m = 0; m < 4; m++) {
    f32x4 x = *(const f32x4*)(ws[m] + i * 4);
    f16x4 h;
#pragma unroll
    for (int j = 0; j < 4; j++) h[j] = (_Float16)x[j];
    *(f16x4*)(os[m] + i * 4) = h;
  }
}

__global__ void cvt_act_kernel(const float* __restrict__ a0, const float* __restrict__ a1,
                               const float* __restrict__ a2, _Float16* __restrict__ o0,
                               _Float16* __restrict__ o1, _Float16* __restrict__ o2) {
  size_t i = (size_t)blockIdx.x * blockDim.x + threadIdx.x;
  const float* as[3] = {a0, a1, a2};
  _Float16* os[3] = {o0, o1, o2};
#pragma unroll
  for (int m = 0; m < 3; m++) {
    f32x4 x = *(const f32x4*)(as[m] + i * 4);
    f16x4 h;
#pragma unroll
    for (int j = 0; j < 4; j++) h[j] = (_Float16)x[j];
    *(f16x4*)(os[m] + i * 4) = h;
  }
}

struct QKVPtrs {
  const float* a32[3];
  const _Float16* a16[3];
  const _Float16* w[3];
  const float* bias[3];
  _Float16* out[3];
};

// ---------------- fused QKV GEMM: C = A[M,K] * W[N,K]^T + bias ----------------
// grid (m=64, n=8, z=3): same-m blocks have linear ids congruent mod 8 -> same XCD L2.
// z=0: Q -> [B,H,T,64] (scaled by QSCALE); z=1: K -> [B,H,T,64]; z=2: V -> [B,H,64,T]
template <bool AH>
__global__ __launch_bounds__(256) void gemm_qkv_kernel(QKVPtrs P) {
  constexpr int K = DM;
  __shared__ __align__(16) _Float16 smem[128 * 144];
  _Float16* As = smem;
  _Float16* Bs = smem + 8192;
  const int z = blockIdx.z;
  const _Float16* Bw = P.w[z];
  const int tid = threadIdx.x;
  const int wave = tid >> 6, lane = tid & 63;
  const int quad = lane >> 4, l16 = lane & 15;
  const int wm = wave >> 1, wn = wave & 1;
  const int m0 = blockIdx.x * 128, n0 = blockIdx.y * 128;
  const float scale = (z == 0) ? QSCALE : 1.0f;

  const f32x4 zero4 = {0.f, 0.f, 0.f, 0.f};
  f32x4 acc[4][4];
#pragma unroll
  for (int mt = 0; mt < 4; mt++)
#pragma unroll
    for (int nt = 0; nt < 4; nt++) acc[mt][nt] = zero4;

  float bv[4];
#pragma unroll
  for (int nt = 0; nt < 4; nt++) bv[nt] = P.bias[z][n0 + wn * 64 + nt * 16 + l16];

  for (int kt = 0; kt < K / 64; kt++) {
    const int k0 = kt * 64;
#pragma unroll
    for (int it = 0; it < 4; it++) {
      int idx = it * 256 + tid;
      async16(Bw + (size_t)(n0 + (idx >> 3)) * K + k0 + (idx & 7) * 8,
              (char*)Bs + (size_t)(it * 256 + wave * 64) * 16);
    }
    if (AH) {
      const _Float16* Af = P.a16[z];
#pragma unroll
      for (int it = 0; it < 4; it++) {
        int idx = it * 256 + tid;
        async16(Af + (size_t)(m0 + (idx >> 3)) * K + k0 + (idx & 7) * 8,
                (char*)As + (size_t)(it * 256 + wave * 64) * 16);
      }
    } else {
      const float* Af = P.a32[z];
#pragma unroll
      for (int it = 0; it < 4; it++) {
        int idx = it * 256 + tid;
        int row = idx >> 3, seg = idx & 7;
        const float* g = Af + (size_t)(m0 + row) * K + k0 + seg * 8;
        f32x4 x0 = *(const f32x4*)g;
        f32x4 x1 = *(const f32x4*)(g + 4);
        f16x8 h;
#pragma unroll
        for (int j = 0; j < 4; j++) { h[j] = (_Float16)x0[j]; h[4 + j] = (_Float16)x1[j]; }
        *(f16x8*)&As[row * 64 + seg * 8] = h;
      }
    }
    __syncthreads();
#pragma unroll
    for (int ks = 0; ks < 2; ks++) {
      f16x8 af[4], bfr[4];
#pragma unroll
      for (int mt = 0; mt < 4; mt++)
        af[mt] = *(const f16x8*)&As[(wm * 64 + mt * 16 + l16) * 64 + ks * 32 + quad * 8];
#pragma unroll
      for (int nt = 0; nt < 4; nt++)
        bfr[nt] = *(const f16x8*)&Bs[(wn * 64 + nt * 16 + l16) * 64 + ks * 32 + quad * 8];
#pragma unroll
      for (int mt = 0; mt < 4; mt++)
#pragma unroll
        for (int nt = 0; nt < 4; nt++)
          acc[mt][nt] = __builtin_amdgcn_mfma_f32_16x16x32_f16(af[mt], bfr[nt], acc[mt][nt], 0, 0, 0);
    }
    __syncthreads();
  }

  // epilogue via LDS (stride 144), coalesced global stores
  _Float16* Ct = smem;
  const int b = m0 >> 11, tbase = m0 & (SEQ - 1);
  if (z < 2) {
#pragma unroll
    for (int mt = 0; mt < 4; mt++)
#pragma unroll
      for (int nt = 0; nt < 4; nt++)
#pragma unroll
        for (int i = 0; i < 4; i++)
          Ct[(wm * 64 + mt * 16 + quad * 4 + i) * 144 + wn * 64 + nt * 16 + l16] =
              (_Float16)((acc[mt][nt][i] + bv[nt]) * scale);
  } else {
#pragma unroll
    for (int mt = 0; mt < 4; mt++)
#pragma unroll
      for (int nt = 0; nt < 4; nt++)
#pragma unroll
        for (int i = 0; i < 4; i++)
          Ct[(wn * 64 + nt * 16 + l16) * 144 + wm * 64 + mt * 16 + quad * 4 + i] =
              (_Float16)(acc[mt][nt][i] + bv[nt]);
  }
  __syncthreads();
  _Float16* out = P.out[z];
  if (z < 2) {
    const int row = tid >> 1, coff = (tid & 1) * 32;
#pragma unroll
    for (int hh = 0; hh < 2; hh++) {
      int h = (n0 >> 6) + hh;
      size_t gb = ((size_t)(b * NH + h) * SEQ + tbase) * 64 + (size_t)tid * 32;
#pragma unroll
      for (int k2 = 0; k2 < 4; k2++)
        *(f16x8*)&out[gb + k2 * 8] =
            *(const f16x8*)&Ct[row * 144 + hh * 64 + coff + k2 * 8];
    }
  } else {
#pragma unroll
    for (int k2 = 0; k2 < 8; k2++) {
      int c = k2 * 256 + tid;
      int n = c >> 4, s2 = c & 15;
      int h = (n0 + n) >> 6, d = (n0 + n) & (DK - 1);
      size_t gb = ((size_t)(b * NH + h) * DK + d) * SEQ + tbase + s2 * 8;
      *(f16x8*)&out[gb] = *(const f16x8*)&Ct[n * 144 + s2 * 8];
    }
  }
}

// ---------------- output GEMM: fp16 A, fp32 out [M, DM]; grid (m=64, n=8) ----------------
__global__ __launch_bounds__(256) void gemm_out_kernel(
    const _Float16* __restrict__ Ah, const _Float16* __restrict__ Bw,
    const float* __restrict__ bias, float* __restrict__ Cp) {
  constexpr int K = DM;
  __shared__ __align__(16) _Float16 As[128 * 64];
  __shared__ __align__(16) _Float16 Bs[128 * 64];
  const int tid = threadIdx.x;
  const int wave = tid >> 6, lane = tid & 63;
  const int quad = lane >> 4, l16 = lane & 15;
  const int wm = wave >> 1, wn = wave & 1;
  const int m0 = blockIdx.x * 128, n0 = blockIdx.y * 128;

  const f32x4 zero4 = {0.f, 0.f, 0.f, 0.f};
  f32x4 acc[4][4];
#pragma unroll
  for (int mt = 0; mt < 4; mt++)
#pragma unroll
    for (int nt = 0; nt < 4; nt++) acc[mt][nt] = zero4;

  float bv[4];
#pragma unroll
  for (int nt = 0; nt < 4; nt++) bv[nt] = bias[n0 + wn * 64 + nt * 16 + l16];

  for (int kt = 0; kt < K / 64; kt++) {
    const int k0 = kt * 64;
#pragma unroll
    for (int it = 0; it < 4; it++) {
      int idx = it * 256 + tid;
      async16(Bw + (size_t)(n0 + (idx >> 3)) * K + k0 + (idx & 7) * 8,
              (char*)Bs + (size_t)(it * 256 + wave * 64) * 16);
    }
#pragma unroll
    for (int it = 0; it < 4; it++) {
      int idx = it * 256 + tid;
      async16(Ah + (size_t)(m0 + (idx >> 3)) * K + k0 + (idx & 7) * 8,
              (char*)As + (size_t)(it * 256 + wave * 64) * 16);
    }
    __syncthreads();
#pragma unroll
    for (int ks = 0; ks < 2; ks++) {
      f16x8 af[4], bfr[4];
#pragma unroll
      for (int mt = 0; mt < 4; mt++)
        af[mt] = *(const f16x8*)&As[(wm * 64 + mt * 16 + l16) * 64 + ks * 32 + quad * 8];
#pragma unroll
      for (int nt = 0; nt < 4; nt++)
        bfr[nt] = *(const f16x8*)&Bs[(wn * 64 + nt * 16 + l16) * 64 + ks * 32 + quad * 8];
#pragma unroll
      for (int mt = 0; mt < 4; mt++)
#pragma unroll
        for (int nt = 0; nt < 4; nt++)
          acc[mt][nt] = __builtin_amdgcn_mfma_f32_16x16x32_f16(af[mt], bfr[nt], acc[mt][nt], 0, 0, 0);
    }
    __syncthreads();
  }
#pragma unroll
  for (int mt = 0; mt < 4; mt++)
#pragma unroll
    for (int nt = 0; nt < 4; nt++)
#pragma unroll
      for (int i = 0; i < 4; i++) {
        int m = m0 + wm * 64 + mt * 16 + quad * 4 + i;
        int n = n0 + wn * 64 + nt * 16 + l16;
        Cp[(size_t)m * DM + n] = acc[mt][nt][i] + bv[nt];
      }
}

// ---------------- transposed-score flash attention (causal) ----------------
// S^T = mfma(A=K, B=Q): lane owns q=l16 -> 2-shuffle row reductions; the S^T C-frag
// IS the A-frag of mfma_f32_16x16x16f16 for PV (k=quad*4+reg) -> no P LDS round-trip.
// Q,K: [B,H,T,64] fp16 (Q pre-scaled); V: [B,H,64,T] fp16; O: [B,T,H*64] fp16.
// Blocks paired {qt, 15-qt}: uniform 17 k-iters. LDS padded: Ks stride 72, Vs stride 136.
__global__ __launch_bounds__(256, 2) void attn_kernel(
    const _Float16* __restrict__ Q, const _Float16* __restrict__ Kt,
    const _Float16* __restrict__ V, _Float16* __restrict__ O) {
  __shared__ __align__(16) _Float16 Ks[128 * 72];
  __shared__ __align__(16) _Float16 Vs[64 * 136];
  const int tid = threadIdx.x;
  const int wave = tid >> 6, lane = tid & 63, quad = lane >> 4, l16 = lane & 15;
  const int bh = blockIdx.y;
  const size_t base = (size_t)bh * SEQ * DK; // same stride for K-layout and V-layout
  const int b = bh >> 4, h = bh & 15;
  const f32x4 zero4 = {0.f, 0.f, 0.f, 0.f};

  for (int p = 0; p < 2; p++) {
    const int qt = (p == 0) ? (int)blockIdx.x : 15 - (int)blockIdx.x;
    const int t0 = qt * 128;

    // Q-frags (B-operand): lane n=l16 -> q-row, k=d=quad*8+j
    f16x8 qf[2][2];
#pragma unroll
    for (int mt = 0; mt < 2; mt++)
#pragma unroll
      for (int ks = 0; ks < 2; ks++)
        qf[mt][ks] = *(const f16x8*)(Q + base + (size_t)(t0 + wave * 32 + mt * 16 + l16) * DK +
                                     ks * 32 + quad * 8);

    f32x4 oacc[2][4];
#pragma unroll
    for (int mt = 0; mt < 2; mt++)
#pragma unroll
      for (int nt = 0; nt < 4; nt++) oacc[mt][nt] = zero4;
    float mrow[2] = {-1e30f, -1e30f}, lrow[2] = {0.f, 0.f};

    for (int j = 0; j <= qt; j++) {
      // stage K [128 tk][64 d] -> Ks (stride 72), V [64 d][128 tk] -> Vs (stride 136)
#pragma unroll
      for (int it = 0; it < 4; it++) {
        int c = it * 256 + tid;
        int row = c >> 3, off = (c & 7) * 8;
        *(f16x8*)&Ks[row * 72 + off] =
            *(const f16x8*)(Kt + base + (size_t)(j * 128 + row) * 64 + off);
      }
#pragma unroll
      for (int it = 0; it < 4; it++) {
        int c = it * 256 + tid;
        int d = c >> 4, off = (c & 15) * 8;
        *(f16x8*)&Vs[d * 136 + off] =
            *(const f16x8*)(V + base + ((size_t)d << 11) + j * 128 + off);
      }
      __syncthreads();

      // S^T frags: rows tk=quad*4+i (within nt*16 block), cols q=l16 (within wave*32+mt*16)
      f32x4 s[2][8];
#pragma unroll
      for (int nt = 0; nt < 8; nt++) {
        f16x8 kf0 = *(const f16x8*)&Ks[(nt * 16 + l16) * 72 + quad * 8];
        f16x8 kf1 = *(const f16x8*)&Ks[(nt * 16 + l16) * 72 + 32 + quad * 8];
#pragma unroll
        for (int mt = 0; mt < 2; mt++) {
          f32x4 zz = zero4;
          zz = __builtin_amdgcn_mfma_f32_16x16x32_f16(kf0, qf[mt][0], zz, 0, 0, 0);
          zz = __builtin_amdgcn_mfma_f32_16x16x32_f16(kf1, qf[mt][1], zz, 0, 0, 0);
          s[mt][nt] = zz;
        }
      }
      if (j == qt) { // diagonal: mask tk_local > q_local
#pragma unroll
        for (int mt = 0; mt < 2; mt++) {
          int qloc = wave * 32 + mt * 16 + l16;
#pragma unroll
          for (int nt = 0; nt < 8; nt++)
#pragma unroll
            for (int i = 0; i < 4; i++)
              if (nt * 16 + quad * 4 + i > qloc) s[mt][nt][i] = -1e30f;
        }
      }
      // online softmax: lane owns q=l16; reduce own 32 vals + xor16/xor32 across quads
#pragma unroll
      for (int mt = 0; mt < 2; mt++) {
        float mx = mrow[mt];
#pragma unroll
        for (int nt = 0; nt < 8; nt++)
#pragma unroll
          for (int i = 0; i < 4; i++) mx = fmaxf(mx, s[mt][nt][i]);
        mx = fmaxf(mx, __shfl_xor(mx, 16));
        mx = fmaxf(mx, __shfl_xor(mx, 32));
        float alpha = __builtin_exp2f(mrow[mt] - mx);
        mrow[mt] = mx;
        float rs = 0.f;
#pragma unroll
        for (int nt = 0; nt < 8; nt++)
#pragma unroll
          for (int i = 0; i < 4; i++) {
            float pv = __builtin_exp2f(s[mt][nt][i] - mx);
            s[mt][nt][i] = pv;
            rs += pv;
          }
        rs += __shfl_xor(rs, 16);
        rs += __shfl_xor(rs, 32);
        lrow[mt] = lrow[mt] * alpha + rs;
        // broadcast alpha to O-row owners (rows q=quad*4+i)
#pragma unroll
        for (int i = 0; i < 4; i++) {
          float ab = __shfl(alpha, quad * 4 + i);
#pragma unroll
          for (int nt = 0; nt < 4; nt++) oacc[mt][nt][i] *= ab;
        }
      }
      // PV: A-frag = cvt(S^T frag) in regs; B-frag = Vs rows (d=l16), k=tk=quad*4+j
#pragma unroll
      for (int jj = 0; jj < 8; jj++) {
        f16x4 pf[2];
#pragma unroll
        for (int mt = 0; mt < 2; mt++) {
          f16x4 t;
#pragma unroll
          for (int i = 0; i < 4; i++) t[i] = (_Float16)s[mt][jj][i];
          pf[mt] = t;
        }
#pragma unroll
        for (int nt = 0; nt < 4; nt++) {
          f16x4 vb = *(const f16x4*)&Vs[(nt * 16 + l16) * 136 + jj * 16 + quad * 4];
#pragma unroll
          for (int mt = 0; mt < 2; mt++)
            oacc[mt][nt] = __builtin_amdgcn_mfma_f32_16x16x16f16(pf[mt], vb, oacc[mt][nt], 0, 0, 0);
        }
      }
      __syncthreads();
    }
    // epilogue: O rows q=quad*4+i, cols d=l16; fetch 1/l via shuffle
#pragma unroll
    for (int mt = 0; mt < 2; mt++) {
      float linv = 1.0f / lrow[mt];
#pragma unroll
      for (int i = 0; i < 4; i++) {
        float lb = __shfl(linv, quad * 4 + i);
        int t = t0 + wave * 32 + mt * 16 + quad * 4 + i;
#pragma unroll
        for (int nt = 0; nt < 4; nt++) {
          int d = nt * 16 + l16;
          O[((size_t)(b * SEQ + t) << 10) + h * 64 + d] = (_Float16)(oacc[mt][nt][i] * lb);
        }
      }
    }
  }
}

extern "C" void kernel_launch(void* const* d_in, const int* in_sizes, int n_in,
                              void* d_out, int out_size, void* d_ws, size_t ws_size,
                              hipStream_t stream) {
  const float* query = (const float*)d_in[0];
  const float* key_  = (const float*)d_in[1];
  const float* value = (const float*)d_in[2];
  const float* W_q = (const float*)d_in[4];
  const float* b_q = (const float*)d_in[5];
  const float* W_k = (const float*)d_in[6];
  const float* b_k = (const float*)d_in[7];
  const float* W_v = (const float*)d_in[8];
  const float* b_v = (const float*)d_in[9];
  const float* W_o = (const float*)d_in[10];
  const float* b_o = (const float*)d_in[11];

  constexpr size_t WEL = (size_t)DM * DM;    // 1M halves
  constexpr size_t MEL = (size_t)MROWS * DM; // 8M halves
  _Float16* ws = (_Float16*)d_ws;
  _Float16* wq = ws;
  _Float16* wk = wq + WEL;
  _Float16* wv = wk + WEL;
  _Float16* wo = wv + WEL;

  // big layout: [weights 8MB][qh kh vh 48MB][qb kb vb 48MB]; ab overlays qh (dead by attn)
  const bool big = ws_size >= (size_t)(4 * WEL + 6 * MEL) * sizeof(_Float16);

  QKVPtrs P;
  P.a32[0] = query; P.a32[1] = key_; P.a32[2] = value;
  P.w[0] = wq; P.w[1] = wk; P.w[2] = wv;
  P.bias[0] = b_q; P.bias[1] = b_k; P.bias[2] = b_v;

  cvt_w_kernel<<<dim3((unsigned)(WEL / 4 / 256)), 256, 0, stream>>>(
      W_q, W_k, W_v, W_o, wq, wk, wv, wo);

  _Float16 *qb, *kb, *vb, *ab;
  if (big) {
    _Float16* qh = wo + WEL;
    _Float16* kh = qh + MEL;
    _Float16* vh = kh + MEL;
    qb = vh + MEL; kb = qb + MEL; vb = kb + MEL;
    ab = qh; // reuse
    P.a16[0] = qh; P.a16[1] = kh; P.a16[2] = vh;
    P.out[0] = qb; P.out[1] = kb; P.out[2] = vb;
    cvt_act_kernel<<<dim3((unsigned)(MEL / 4 / 256)), 256, 0, stream>>>(
        query, key_, value, qh, kh, vh);
    gemm_qkv_kernel<true><<<dim3(MROWS / 128, DM / 128, 3), 256, 0, stream>>>(P);
  } else {
    qb = wo + WEL; kb = qb + MEL; vb = kb + MEL; ab = vb + MEL;
    P.a16[0] = P.a16[1] = P.a16[2] = nullptr;
    P.out[0] = qb; P.out[1] = kb; P.out[2] = vb;
    gemm_qkv_kernel<false><<<dim3(MROWS / 128, DM / 128, 3), 256, 0, stream>>>(P);
  }

  attn_kernel<<<dim3(8, BATCH * NH), 256, 0, stream>>>(qb, kb, vb, ab);

  gemm_out_kernel<<<dim3(MROWS / 128, DM / 128), 256, 0, stream>>>(ab, wo, b_o, (float*)d_out);
}